// Round 2
// baseline (82.320 us; speedup 1.0000x reference)
//
#include <hip/hip_runtime.h>

// CARAFE: features [B=2, h=64, w=64, C0=256] f32, masks [B, H=128, W=128, 25] f32,
// k=5, group=1. Nearest-upsample (half-pixel, 2x) == Y//2.
// out[b,Y,X,c] = sum_{di,dj} M[b,Y,X,di*5+dj] * F[b, Y/2+di-2, X/2+dj-2, c] (zero pad).
//
// One wave64 per low-res pixel: the 2x2 output quad (2y0..2y0+1, 2x0..2x0+1)
// shares all 25 feature-patch float4 loads. Lane i covers channels 4i..4i+3.
// Block = 256 threads = 4 waves = 4 quads.
//
// BRANCHLESS body: tap coords clamped to the edge (loads always in-bounds),
// loaded vector scaled by a 0/1 validity factor. No exec-mask manipulation
// anywhere — R1's 25x-unrolled predicated-load structure failed the
// post-timing re-validation; this is the straight-line replacement.

#define C0   256
#define HLO  64
#define WLO  64
#define HHI  128
#define WHI  128
#define K    5
#define KK   25

__global__ __launch_bounds__(256) void carafe_quad_kernel(
    const float* __restrict__ feat,   // [B, 64, 64, 256]
    const float* __restrict__ mask,   // [B, 128, 128, 25]
    float* __restrict__ out)          // [B, 128, 128, 256]
{
    const int wid  = blockIdx.x * 4 + (threadIdx.x >> 6);  // b*4096 + y0*64 + x0
    const int lane = threadIdx.x & 63;
    const int c    = lane * 4;

    const int b  = wid >> 12;
    const int y0 = (wid >> 6) & 63;
    const int x0 = wid & 63;

    const int Y0 = y0 * 2;
    const int X0 = x0 * 2;

    const float* fbase = feat + ((size_t)b * HLO * WLO) * C0 + c;
    const float* mbase = mask + ((size_t)((b * HHI + Y0) * WHI + X0)) * KK;
    const float* m00 = mbase;                 // (Y0,   X0)
    const float* m01 = mbase + KK;            // (Y0,   X0+1)
    const float* m10 = mbase + WHI * KK;      // (Y0+1, X0)
    const float* m11 = mbase + WHI * KK + KK; // (Y0+1, X0+1)

    float4 a00 = make_float4(0.f, 0.f, 0.f, 0.f);
    float4 a01 = make_float4(0.f, 0.f, 0.f, 0.f);
    float4 a10 = make_float4(0.f, 0.f, 0.f, 0.f);
    float4 a11 = make_float4(0.f, 0.f, 0.f, 0.f);

    #pragma unroll
    for (int di = 0; di < K; ++di) {
        const int   y  = y0 + di - 2;
        const int   yc = min(max(y, 0), HLO - 1);
        const float vy = ((unsigned)y < (unsigned)HLO) ? 1.f : 0.f;
        #pragma unroll
        for (int dj = 0; dj < K; ++dj) {
            const int   x  = x0 + dj - 2;
            const int   xc = min(max(x, 0), WLO - 1);
            const float v  = ((unsigned)x < (unsigned)WLO) ? vy : 0.f;

            // Always-in-bounds load (clamped), then scale by validity.
            float4 f = *(const float4*)(fbase + (size_t)(yc * WLO + xc) * C0);
            f.x *= v; f.y *= v; f.z *= v; f.w *= v;

            const int p = di * K + dj;
            const float w00 = m00[p];
            const float w01 = m01[p];
            const float w10 = m10[p];
            const float w11 = m11[p];
            a00.x = fmaf(f.x, w00, a00.x); a00.y = fmaf(f.y, w00, a00.y);
            a00.z = fmaf(f.z, w00, a00.z); a00.w = fmaf(f.w, w00, a00.w);
            a01.x = fmaf(f.x, w01, a01.x); a01.y = fmaf(f.y, w01, a01.y);
            a01.z = fmaf(f.z, w01, a01.z); a01.w = fmaf(f.w, w01, a01.w);
            a10.x = fmaf(f.x, w10, a10.x); a10.y = fmaf(f.y, w10, a10.y);
            a10.z = fmaf(f.z, w10, a10.z); a10.w = fmaf(f.w, w10, a10.w);
            a11.x = fmaf(f.x, w11, a11.x); a11.y = fmaf(f.y, w11, a11.y);
            a11.z = fmaf(f.z, w11, a11.z); a11.w = fmaf(f.w, w11, a11.w);
        }
    }

    float* obase = out + ((size_t)((b * HHI + Y0) * WHI + X0)) * C0 + c;
    *(float4*)(obase)                 = a00;
    *(float4*)(obase + C0)            = a01;
    *(float4*)(obase + WHI * C0)      = a10;
    *(float4*)(obase + WHI * C0 + C0) = a11;
}

extern "C" void kernel_launch(void* const* d_in, const int* in_sizes, int n_in,
                              void* d_out, int out_size, void* d_ws, size_t ws_size,
                              hipStream_t stream) {
    const float* feat = (const float*)d_in[0];   // 2*64*64*256
    const float* mask = (const float*)d_in[1];   // 2*128*128*25
    float* out = (float*)d_out;                  // 2*128*128*256

    // waves = B*h*w = 2*64*64 = 8192; 4 waves (quads) per 256-thread block.
    carafe_quad_kernel<<<8192 / 4, 256, 0, stream>>>(feat, mask, out);
}

// Round 3
// 79.895 us; speedup vs baseline: 1.0304x; 1.0304x over previous
//
#include <hip/hip_runtime.h>

// CARAFE: features [B=2, h=64, w=64, C0=256] f32, masks [B, H=128, W=128, 25] f32,
// k=5, group=1. Nearest-upsample (half-pixel, 2x) == Y//2.
// out[b,Y,X,c] = sum_{di,dj} M[b,Y,X,di*5+dj] * F[b, Y/2+di-2, X/2+dj-2, c] (zero pad).
//
// One wave64 per low-res pixel: the 2x2 output quad shares all 25 feature
// float4 loads. Lane i covers channels 4i..4i+3. Block = 256 = 4 waves.
//
// R3 change: wid is forced scalar with readfirstlane, so ALL mask loads
// (100 per wave, wave-uniform addresses) compile to s_load through the
// constant cache instead of 100 vector VMEM broadcasts, and feature tap
// addressing is SGPR-side. Vector VMEM per wave: 129 -> 29.
// Body stays branchless (R1's exec-mask predication failed post-timing
// re-validation; clamp+0/1-scale is the stable form).

#define C0   256
#define HLO  64
#define WLO  64
#define HHI  128
#define WHI  128
#define K    5
#define KK   25

__global__ __launch_bounds__(256) void carafe_quad_kernel(
    const float* __restrict__ feat,   // [B, 64, 64, 256]
    const float* __restrict__ mask,   // [B, 128, 128, 25]
    float* __restrict__ out)          // [B, 128, 128, 256]
{
    // Wave-uniform quad id, made *provably* scalar for the backend.
    const int wid = __builtin_amdgcn_readfirstlane(
        blockIdx.x * 4 + (threadIdx.x >> 6));   // b*4096 + y0*64 + x0
    const int lane = threadIdx.x & 63;
    const int c    = lane * 4;                  // per-lane channel offset

    const int b  = wid >> 12;
    const int y0 = (wid >> 6) & 63;
    const int x0 = wid & 63;

    const int Y0 = y0 * 2;
    const int X0 = x0 * 2;

    // Scalar base pointers (all derived from scalar wid).
    const float* fbase = feat + ((size_t)b * HLO * WLO) * C0;   // + tap*C0 + c
    const float* mbase = mask + ((size_t)((b * HHI + Y0) * WHI + X0)) * KK;
    const float* m00 = mbase;                 // (Y0,   X0)
    const float* m01 = mbase + KK;            // (Y0,   X0+1)
    const float* m10 = mbase + WHI * KK;      // (Y0+1, X0)
    const float* m11 = mbase + WHI * KK + KK; // (Y0+1, X0+1)

    float4 a00 = make_float4(0.f, 0.f, 0.f, 0.f);
    float4 a01 = make_float4(0.f, 0.f, 0.f, 0.f);
    float4 a10 = make_float4(0.f, 0.f, 0.f, 0.f);
    float4 a11 = make_float4(0.f, 0.f, 0.f, 0.f);

    #pragma unroll
    for (int di = 0; di < K; ++di) {
        const int   y  = y0 + di - 2;
        const int   yc = min(max(y, 0), HLO - 1);      // scalar
        const float vy = ((unsigned)y < (unsigned)HLO) ? 1.f : 0.f;
        #pragma unroll
        for (int dj = 0; dj < K; ++dj) {
            const int   x  = x0 + dj - 2;
            const int   xc = min(max(x, 0), WLO - 1);  // scalar
            const float v  = ((unsigned)x < (unsigned)WLO) ? vy : 0.f;

            // SGPR base + scalar tap offset + per-lane channel offset.
            float4 f = *(const float4*)(fbase + (size_t)(yc * WLO + xc) * C0 + c);
            f.x *= v; f.y *= v; f.z *= v; f.w *= v;

            const int p = di * K + dj;
            const float w00 = m00[p];   // scalar loads (uniform address)
            const float w01 = m01[p];
            const float w10 = m10[p];
            const float w11 = m11[p];
            a00.x = fmaf(f.x, w00, a00.x); a00.y = fmaf(f.y, w00, a00.y);
            a00.z = fmaf(f.z, w00, a00.z); a00.w = fmaf(f.w, w00, a00.w);
            a01.x = fmaf(f.x, w01, a01.x); a01.y = fmaf(f.y, w01, a01.y);
            a01.z = fmaf(f.z, w01, a01.z); a01.w = fmaf(f.w, w01, a01.w);
            a10.x = fmaf(f.x, w10, a10.x); a10.y = fmaf(f.y, w10, a10.y);
            a10.z = fmaf(f.z, w10, a10.z); a10.w = fmaf(f.w, w10, a10.w);
            a11.x = fmaf(f.x, w11, a11.x); a11.y = fmaf(f.y, w11, a11.y);
            a11.z = fmaf(f.z, w11, a11.z); a11.w = fmaf(f.w, w11, a11.w);
        }
    }

    float* obase = out + ((size_t)((b * HHI + Y0) * WHI + X0)) * C0 + c;
    *(float4*)(obase)                 = a00;
    *(float4*)(obase + C0)            = a01;
    *(float4*)(obase + WHI * C0)      = a10;
    *(float4*)(obase + WHI * C0 + C0) = a11;
}

extern "C" void kernel_launch(void* const* d_in, const int* in_sizes, int n_in,
                              void* d_out, int out_size, void* d_ws, size_t ws_size,
                              hipStream_t stream) {
    const float* feat = (const float*)d_in[0];   // 2*64*64*256
    const float* mask = (const float*)d_in[1];   // 2*128*128*25
    float* out = (float*)d_out;                  // 2*128*128*256

    // waves = B*h*w = 2*64*64 = 8192; 4 waves (quads) per 256-thread block.
    carafe_quad_kernel<<<8192 / 4, 256, 0, stream>>>(feat, mask, out);
}

// Round 4
// 79.613 us; speedup vs baseline: 1.0340x; 1.0035x over previous
//
#include <hip/hip_runtime.h>

// CARAFE: features [B=2, h=64, w=64, C0=256] f32, masks [B, H=128, W=128, 25] f32,
// k=5, group=1. Nearest-upsample (half-pixel, 2x) == Y//2.
// out[b,Y,X,c] = sum_{di,dj} M[b,Y,X,di*5+dj] * F[b, Y/2+di-2, X/2+dj-2, c] (zero pad).
//
// R4:
//  - Each wave64 handles TWO x-adjacent low-res pixels (a 2x4 output block):
//    tap union is 5x6 = 30 float4 loads for 2 quads (vs 2x25), cutting feature
//    VMEM instructions 40%. Lane i covers channels 4i..4i+3.
//  - XCD-aware blockIdx swizzle: with round-robin block->XCD placement,
//    bid&7 selects the XCD; we give each XCD 16 contiguous global rows so its
//    feature working set (~1.3 MB incl. halo) fits the 4 MiB per-XCD L2,
//    recovering the 25x tap-overlap reuse that round-robin placement spreads
//    across incoherent L2s.
//  - Body stays branchless wrt data (clamp + 0/1 scale); the t<=4 / t>=1
//    guards are compile-time after full unroll. (R1's runtime exec-mask
//    predication failed post-timing re-validation; never again.)
//  - wid components forced scalar via readfirstlane so mask reads stay s_load.

#define C0   256
#define HLO  64
#define WLO  64
#define HHI  128
#define WHI  128
#define K    5
#define KK   25

__global__ __launch_bounds__(256) void carafe_kernel(
    const float* __restrict__ feat,   // [B, 64, 64, 256]
    const float* __restrict__ mask,   // [B, 128, 128, 25]
    float* __restrict__ out)          // [B, 128, 128, 256]
{
    // --- scalar (wave-uniform) tile coordinates ---
    const int wv   = __builtin_amdgcn_readfirstlane(threadIdx.x >> 6); // 0..3
    const int bid  = blockIdx.x;          // 0..1023
    const int xcd  = bid & 7;             // round-robin XCD slot (heuristic)
    const int i    = bid >> 3;            // 0..127
    const int r    = xcd * 16 + (i & 15); // global row 0..127 (contiguous per XCD)
    const int xblk = i >> 4;              // 0..7
    const int b    = r >> 6;
    const int y0   = r & 63;
    const int x0   = xblk * 8 + wv * 2;   // low-res col of first quad
    const int lane = threadIdx.x & 63;
    const int c    = lane * 4;            // per-lane channel offset

    const int Y0 = y0 * 2;
    const int X0 = x0 * 2;

    const float* fbase = feat + (size_t)b * HLO * WLO * C0;
    const float* mrow0 = mask + (size_t)((b * HHI + Y0) * WHI + X0) * KK;
    const float* mrow1 = mrow0 + WHI * KK;

    // acc[row][qq]: output pixel (Y0+row, X0+qq), 4 channels each.
    float4 acc[2][4];
    #pragma unroll
    for (int rr = 0; rr < 2; ++rr)
        #pragma unroll
        for (int qq = 0; qq < 4; ++qq)
            acc[rr][qq] = make_float4(0.f, 0.f, 0.f, 0.f);

    #pragma unroll
    for (int di = 0; di < K; ++di) {
        const int   y  = y0 + di - 2;
        const int   yc = min(max(y, 0), HLO - 1);
        const float vy = ((unsigned)y < (unsigned)HLO) ? 1.f : 0.f;
        #pragma unroll
        for (int t = 0; t < 6; ++t) {           // tap col x0 + t - 2
            const int   x  = x0 + t - 2;
            const int   xc = min(max(x, 0), WLO - 1);
            const float v  = ((unsigned)x < (unsigned)WLO) ? vy : 0.f;

            float4 f = *(const float4*)(fbase + (size_t)(yc * WLO + xc) * C0 + c);
            f.x *= v; f.y *= v; f.z *= v; f.w *= v;

            // quad 0 (out cols qq=0,1): dj = t, valid for t<=4  (compile-time)
            if (t <= 4) {
                const int p = di * K + t;
                #pragma unroll
                for (int rr = 0; rr < 2; ++rr) {
                    const float* mr = rr ? mrow1 : mrow0;
                    #pragma unroll
                    for (int qq = 0; qq < 2; ++qq) {
                        const float wgt = mr[qq * KK + p];
                        acc[rr][qq].x = fmaf(f.x, wgt, acc[rr][qq].x);
                        acc[rr][qq].y = fmaf(f.y, wgt, acc[rr][qq].y);
                        acc[rr][qq].z = fmaf(f.z, wgt, acc[rr][qq].z);
                        acc[rr][qq].w = fmaf(f.w, wgt, acc[rr][qq].w);
                    }
                }
            }
            // quad 1 (out cols qq=2,3): dj = t-1, valid for t>=1 (compile-time)
            if (t >= 1) {
                const int p = di * K + t - 1;
                #pragma unroll
                for (int rr = 0; rr < 2; ++rr) {
                    const float* mr = rr ? mrow1 : mrow0;
                    #pragma unroll
                    for (int qq = 2; qq < 4; ++qq) {
                        const float wgt = mr[qq * KK + p];
                        acc[rr][qq].x = fmaf(f.x, wgt, acc[rr][qq].x);
                        acc[rr][qq].y = fmaf(f.y, wgt, acc[rr][qq].y);
                        acc[rr][qq].z = fmaf(f.z, wgt, acc[rr][qq].z);
                        acc[rr][qq].w = fmaf(f.w, wgt, acc[rr][qq].w);
                    }
                }
            }
        }
    }

    float* ob = out + (size_t)((b * HHI + Y0) * WHI + X0) * C0 + c;
    #pragma unroll
    for (int rr = 0; rr < 2; ++rr)
        #pragma unroll
        for (int qq = 0; qq < 4; ++qq)
            *(float4*)(ob + (size_t)(rr * WHI + qq) * C0) = acc[rr][qq];
}

extern "C" void kernel_launch(void* const* d_in, const int* in_sizes, int n_in,
                              void* d_out, int out_size, void* d_ws, size_t ws_size,
                              hipStream_t stream) {
    const float* feat = (const float*)d_in[0];   // 2*64*64*256
    const float* mask = (const float*)d_in[1];   // 2*128*128*25
    float* out = (float*)d_out;                  // 2*128*128*256

    // 2 batches * 64 rows * 8 x-blocks = 1024 blocks; 4 waves/block,
    // each wave = 2 low-res pixels (2x4 output pixels).
    carafe_kernel<<<1024, 256, 0, stream>>>(feat, mask, out);
}